// Round 9
// baseline (288.360 us; speedup 1.0000x reference)
//
#include <hip/hip_runtime.h>
#include <stdint.h>

typedef unsigned long long u64;
typedef unsigned int u32;

#define BN 2
#define DD 32
#define HH 192
#define WW 192
#define NV (DD*HH*WW)   /* 1179648 */
#define KK 8
#define NSL_S 576       /* k_stats blocks per batch (2048 vox each) */
#define VPB_S 2048
#define NSL_H 288       /* k_hist blocks per batch (4096 vox each) */
#define VPB_H 4096
#define NB 256          /* buckets in window */
#define BOFF 1808       /* 0x38800000>>19 : window floor e = 2^-14 */
#define SCALE 4294967296.0f
#define L2E 1.44269504f

__device__ __forceinline__ u64 fx(float v){ return (u64)(long long)llrintf(v*SCALE); }
__device__ __forceinline__ float unfx(u64 v){ return (float)((double)(long long)v*(1.0/4294967296.0)); }
__device__ __forceinline__ float rcp_f(float x){ return __builtin_amdgcn_rcpf(x); }
__device__ __forceinline__ float exp2_f(float x){ return __builtin_amdgcn_exp2f(x); }
__device__ __forceinline__ float tanh_f(float x){ return 1.f - 2.f*rcp_f(1.f + exp2_f(x*(2.f*L2E))); }
__device__ __forceinline__ float sigm_f(float x){ return rcp_f(1.f + exp2_f(-x*L2E)); }
__device__ __forceinline__ float rfl(float x){ return __uint_as_float(__builtin_amdgcn_readfirstlane((int)__float_as_uint(x))); }

// ---------------- detection of center_images storage layout ----------------
__global__ void k_detect(const u32* __restrict__ w, int nwords, u32* flags){
    u32 fF=0,fB=0,fO=0,f1=0;
    for (int i = blockIdx.x*blockDim.x + threadIdx.x; i < nwords; i += gridDim.x*blockDim.x){
        u32 x = w[i];
        if (x == 0x3F800000u) fF = 1;
        else if (x > 1u) fB = 1;
        else if (x == 1u){ f1 = 1; if (i & 1) fO = 1; }
    }
    if (fF) atomicOr(&flags[0], 1u);
    if (fB) atomicOr(&flags[1], 1u);
    if (fO) atomicOr(&flags[2], 1u);
    if (f1) atomicOr(&flags[3], 1u);
}

// ---------------- per-instance statistics + fused tail-derive ----------------
// ssh[shard(4)][b][k][12]: 0 cnt<<32|cm_cnt, 1..3 sum_xyz, 4..6 m_sig, 7 m_sig2, 8..10 cm_xyz
// derived[(b*KK+k)*8]: 0..2 s_exp, 3..5 center, 6 gts(count), 7 coef(valid/obj)
__global__ __launch_bounds__(512, 8) void k_stats(
        const float* __restrict__ pred,
        const int* __restrict__ inst, const int* __restrict__ lab,
        const void* __restrict__ cim, const u32* __restrict__ flags,
        u64* __restrict__ ssh, u64* __restrict__ bgsh,
        float* __restrict__ derived, float* __restrict__ var_part,
        u32* __restrict__ stk){
    int sx = blockIdx.x, b = blockIdx.y;
    __shared__ u64 bins[8][4][KK][9];   /* 32 replicas, odd inner stride: 18 KB */
    __shared__ u64 cmb[8][KK][4];        /* rare cm sums, per-wave: 2 KB */
    __shared__ u64 bgsum;
    for (int i = threadIdx.x; i < 8*4*KK*9; i += 512) ((u64*)bins)[i] = 0ull;
    for (int i = threadIdx.x; i < 8*KK*4; i += 512) ((u64*)cmb)[i] = 0ull;
    if (threadIdx.x == 0) bgsum = 0ull;
    __syncthreads();
    int mode = flags[0] ? 2 : (flags[1] ? 1 : (flags[2] ? 0 : (flags[3] ? 3 : 0)));
    const float* pb = pred + (size_t)b*7*NV;
    const int* ib = inst + (size_t)b*NV;
    const int* lb = lab + (size_t)b*NV;
    int wv = threadIdx.x >> 6, lp = threadIdx.x & 3;
    int g = sx*VPB_S + threadIdx.x*4;

    float4 s0v = *(const float4*)&pb[3*(size_t)NV + g];
    float4 s1v = *(const float4*)&pb[4*(size_t)NV + g];
    float4 s2v = *(const float4*)&pb[5*(size_t)NV + g];
    float4 s6v = *(const float4*)&pb[6*(size_t)NV + g];
    int4 iv4 = *(const int4*)&ib[g];
    int4 lb4 = *(const int4*)&lb[g];
    int iy = g / WW;
    int ix = g - iy*WW;
    int iz = iy / HH; iy -= iz*HH;
    u64 fdx = fx(1.f/(WW-1));
    u64 fxm = fx(ix*(1.f/(WW-1)));
    u64 fym = fx(iy*(1.f/(HH-1)));
    u64 fzm = fx(iz*(1.f/(DD-1)));
    u32 cv4 = 0;
    size_t gi = (size_t)b*NV + g;
    if (mode == 0){
        int4 c = *(const int4*)&((const int*)cim)[gi];
        cv4 = (c.x?1u:0u)|(c.y?2u:0u)|(c.z?4u:0u)|(c.w?8u:0u);
    } else if (mode == 1){
        u32 c = *(const u32*)&((const unsigned char*)cim)[gi];
        cv4 = ((c&0xFFu)?1u:0u)|((c&0xFF00u)?2u:0u)|((c&0xFF0000u)?4u:0u)|((c&0xFF000000u)?8u:0u);
    } else if (mode == 2){
        float4 c = *(const float4*)&((const float*)cim)[gi];
        cv4 = (c.x!=0.f?1u:0u)|(c.y!=0.f?2u:0u)|(c.z!=0.f?4u:0u)|(c.w!=0.f?8u:0u);
    } else {
        int4 c0 = *(const int4*)&((const int*)cim)[2*gi];
        int4 c1 = *(const int4*)&((const int*)cim)[2*gi + 4];
        cv4 = (c0.x?1u:0u)|(c0.z?2u:0u)|(c1.x?4u:0u)|(c1.z?8u:0u);
    }
    float s0a[4] = {s0v.x,s0v.y,s0v.z,s0v.w};
    float s1a[4] = {s1v.x,s1v.y,s1v.z,s1v.w};
    float s2a[4] = {s2v.x,s2v.y,s2v.z,s2v.w};
    float s6a[4] = {s6v.x,s6v.y,s6v.z,s6v.w};
    int iva[4] = {iv4.x,iv4.y,iv4.z,iv4.w};
    int lba[4] = {lb4.x,lb4.y,lb4.z,lb4.w};
    float bgacc = 0.f;
    #pragma unroll
    for (int j = 0; j < 4; j++){
        float seed = sigm_f(s6a[j]);
        if (lba[j] == 0) bgacc += seed*seed;
        int iv = iva[j];
        if (iv >= 1 && iv <= KK){
            u64* bn = &bins[wv][lp][iv-1][0];
            u32 cv = (cv4 >> j) & 1u;
            atomicAdd(&bn[0], (1ull << 32) | (u64)cv);
            atomicAdd(&bn[1], fxm + (u64)j*fdx);
            atomicAdd(&bn[2], fym);
            atomicAdd(&bn[3], fzm);
            atomicAdd(&bn[4], fx(s0a[j]));
            atomicAdd(&bn[5], fx(s1a[j]));
            atomicAdd(&bn[6], fx(s2a[j]));
            atomicAdd(&bn[7], fx(s0a[j]*s0a[j] + s1a[j]*s1a[j] + s2a[j]*s2a[j]));
            if (cv){
                u64* cb = &cmb[wv][iv-1][0];
                atomicAdd(&cb[0], fxm + (u64)j*fdx);
                atomicAdd(&cb[1], fym);
                atomicAdd(&cb[2], fzm);
            }
        }
    }
    #pragma unroll
    for (int off = 32; off > 0; off >>= 1) bgacc += __shfl_down(bgacc, off);
    if ((threadIdx.x & 63) == 0 && bgacc != 0.f) atomicAdd(&bgsum, fx(bgacc));
    __syncthreads();
    if (threadIdx.x == 0 && bgsum) atomicAdd(&bgsh[(size_t)b*8 + (sx&7)], bgsum);
    for (int i = threadIdx.x; i < KK*8; i += 512){
        int k = i >> 3, s = i & 7;
        u64 acc = 0ull;
        #pragma unroll
        for (int r = 0; r < 32; r++) acc += bins[r>>2][r&3][k][s];
        if (acc) atomicAdd(&ssh[((size_t)((sx&3)*BN + b)*KK + k)*12 + s], acc);
    }
    for (int i = threadIdx.x; i < KK*3; i += 512){
        int k = i / 3, s = i - k*3;
        u64 acc = 0ull;
        #pragma unroll
        for (int w = 0; w < 8; w++) acc += cmb[w][k][s];
        if (acc) atomicAdd(&ssh[((size_t)((sx&3)*BN + b)*KK + k)*12 + 8 + s], acc);
    }
    /* ---- tail-block derive (ticket pattern) ---- */
    __threadfence();
    __syncthreads();              /* ALL waves' global atomics issued before ticket */
    __shared__ u32 lastf;
    if (threadIdx.x == 0){
        u32 tk = __hip_atomic_fetch_add(stk, 1u, __ATOMIC_ACQ_REL, __HIP_MEMORY_SCOPE_AGENT);
        lastf = (tk == (u32)(NSL_S*BN - 1)) ? 1u : 0u;
    }
    __syncthreads();
    if (!lastf) return;
    __threadfence();
    int t = threadIdx.x;
    __shared__ float s_val[16], s_vrk[16], s_obj[2];
    if (t < 16){
        int bb = t >> 3, kq = t & 7;
        u64 st[12];
        #pragma unroll
        for (int s = 0; s < 12; s++){
            u64 a = 0ull;
            #pragma unroll
            for (int sh = 0; sh < 4; sh++)
                a += __hip_atomic_load(&ssh[((size_t)(sh*BN + bb)*KK + kq)*12 + s],
                                       __ATOMIC_ACQUIRE, __HIP_MEMORY_SCOPE_AGENT);
            st[s] = a;
        }
        float cnt = (float)(long long)(st[0] >> 32);
        float cmc = (float)(u32)(st[0] & 0xFFFFFFFFull);
        float sxs = unfx(st[1]), sys = unfx(st[2]), szs = unfx(st[3]);
        float g0 = unfx(st[4]), g1 = unfx(st[5]), g2 = unfx(st[6]);
        float h = unfx(st[7]);
        float cmx = unfx(st[8]), cmy = unfx(st[9]), cmz = unfx(st[10]);
        float valid = cnt > 0.f ? 1.f : 0.f;
        float safe = fmaxf(cnt, 1.f);
        float c0 = (cmc == 1.f) ? cmx : sxs/safe;
        float c1 = (cmc == 1.f) ? cmy : sys/safe;
        float c2 = (cmc == 1.f) ? cmz : szs/safe;
        float sm0 = g0/safe, sm1 = g1/safe, sm2 = g2/safe;
        float vs = h - 2.f*(sm0*g0 + sm1*g1 + sm2*g2)
                 + (sm0*sm0 + sm1*sm1 + sm2*sm2)*cnt;
        s_vrk[t] = vs / (3.f*safe);
        s_val[t] = valid;
        float* dd = &derived[(size_t)t*8];
        dd[0] = expf(10.f*sm0); dd[1] = expf(10.f*sm1); dd[2] = expf(10.f*sm2);
        dd[3] = c0; dd[4] = c1; dd[5] = c2; dd[6] = cnt;
    }
    __syncthreads();
    if (t < 2){
        float obj = 0.f, vp = 0.f;
        #pragma unroll
        for (int kq = 0; kq < 8; kq++){
            obj += s_val[t*8 + kq];
            vp += s_val[t*8 + kq]*s_vrk[t*8 + kq];
        }
        obj = fmaxf(obj, 1.f);
        var_part[t] = vp / obj;
        s_obj[t] = obj;
    }
    __syncthreads();
    if (t < 16) derived[(size_t)t*8 + 7] = s_val[t]/s_obj[t >> 3];
}

// ---------------- single-pass all-k windowed histogram, 8 vox/thread ----------------
__global__ __launch_bounds__(512, 4) void k_hist(
        const float* __restrict__ pred,
        const int* __restrict__ inst, const float* __restrict__ derived,
        u32* __restrict__ hs, u64* __restrict__ bgsh){
    __shared__ u32 lh[KK*2*NB];   /* 16 KB */
    __shared__ u64 fgfx;
    int sx = blockIdx.x, b = blockIdx.y;
    if (threadIdx.x == 0) fgfx = 0ull;
    for (int i = threadIdx.x; i < KK*2*NB; i += 512) lh[i] = 0u;
    float ax[KK], ay[KK], az[KK], cx[KK], cy[KK], cz[KK];
    const float* db = derived + (size_t)b*KK*8;
    #pragma unroll
    for (int k = 0; k < KK; k++){
        ax[k]=rfl(db[k*8+0])*L2E; ay[k]=rfl(db[k*8+1])*L2E; az[k]=rfl(db[k*8+2])*L2E;
        cx[k]=rfl(db[k*8+3]); cy[k]=rfl(db[k*8+4]); cz[k]=rfl(db[k*8+5]);
    }
    __syncthreads();
    const float* pb = pred + (size_t)b*7*NV;
    const int* ib = inst + (size_t)b*NV;
    int g = sx*VPB_H + threadIdx.x*8;
    const float4* q0 = (const float4*)&pb[g];
    const float4* q1 = (const float4*)&pb[(size_t)NV + g];
    const float4* q2 = (const float4*)&pb[2*(size_t)NV + g];
    const float4* q6 = (const float4*)&pb[6*(size_t)NV + g];
    float4 a0 = q0[0], b0 = q0[1];
    float4 a1 = q1[0], b1 = q1[1];
    float4 a2 = q2[0], b2 = q2[1];
    float4 a6 = q6[0], b6 = q6[1];
    const int4* qi = (const int4*)&ib[g];
    int4 i0 = qi[0], i1 = qi[1];
    int iy = g / WW;
    int ix = g - iy*WW;
    int iz = iy / HH; iy -= iz*HH;
    float xm = ix*(1.f/(WW-1)), ym = iy*(1.f/(HH-1)), zm = iz*(1.f/(DD-1));
    float p0a[8] = {a0.x,a0.y,a0.z,a0.w,b0.x,b0.y,b0.z,b0.w};
    float p1a[8] = {a1.x,a1.y,a1.z,a1.w,b1.x,b1.y,b1.z,b1.w};
    float p2a[8] = {a2.x,a2.y,a2.z,a2.w,b2.x,b2.y,b2.z,b2.w};
    float p6a[8] = {a6.x,a6.y,a6.z,a6.w,b6.x,b6.y,b6.z,b6.w};
    int iva[8] = {i0.x,i0.y,i0.z,i0.w,i1.x,i1.y,i1.z,i1.w};
    float e0[8], e1[8], e2[8], sd[8];
    #pragma unroll
    for (int j = 0; j < 8; j++){
        e0[j] = tanh_f(p0a[j]) + xm + j*(1.f/(WW-1));
        e1[j] = tanh_f(p1a[j]) + ym;
        e2[j] = tanh_f(p2a[j]) + zm;
        sd[j] = sigm_f(p6a[j]);
    }
    float fgacc = 0.f;
    #pragma unroll
    for (int k = 0; k < KK; k++){
        #pragma unroll
        for (int j = 0; j < 8; j++){
            float d0 = e0[j] - cx[k], d1 = e1[j] - cy[k], dz = e2[j] - cz[k];
            float d2 = ax[k]*d0*d0;
            d2 = fmaf(ay[k]*d1, d1, d2);
            d2 = fmaf(az[k]*dz, dz, d2);
            float dist = exp2_f(-d2);               /* L2E folded into a's */
            if (iva[j] == k + 1){
                float e = fmaf(-2.f, dist, 2.f);
                int bu = (int)(__float_as_uint(e) >> 19) - BOFF;
                bu = bu < 0 ? 0 : (bu > NB-1 ? NB-1 : bu);
                atomicAdd(&lh[k*512 + bu], 1u);
                fgacc += (sd[j] - dist)*(sd[j] - dist);
            } else {
                /* e = 2*dist: bits(2x)>>19 == (bits(x)>>19)+16 for normals */
                int bu = (int)(__float_as_uint(dist) >> 19) - (BOFF - 16);
                bu = bu < 0 ? 0 : (bu > NB-1 ? NB-1 : bu);
                atomicAdd(&lh[k*512 + NB + bu], 1u);
            }
        }
    }
    #pragma unroll
    for (int off = 32; off > 0; off >>= 1) fgacc += __shfl_down(fgacc, off);
    if ((threadIdx.x & 63) == 0 && fgacc != 0.f) atomicAdd(&fgfx, fx(fgacc));
    __syncthreads();
    if (threadIdx.x == 0 && fgfx) atomicAdd(&bgsh[(size_t)(2+b)*8 + (sx&7)], fgfx);
    u32* out = hs + ((size_t)b*NSL_H + sx)*(KK*NB);
    for (int i = threadIdx.x; i < KK*NB; i += 512){
        int k = i >> 8, bu = i & 255;
        out[i] = (lh[k*512 + bu] << 16) | lh[k*512 + NB + bu];
    }
}

// ---------------- two-stage Lovasz: 4 partial blocks per (b,k) + tail scan + fused final ----------------
__global__ __launch_bounds__(512) void k_lovasz(
        const u32* __restrict__ hs, const float* __restrict__ derived,
        u64* __restrict__ ph, u32* __restrict__ tkb,
        float* __restrict__ lov, const float* __restrict__ var_part,
        const u64* __restrict__ bgsh, u32* __restrict__ counter,
        float* __restrict__ out){
    int bk = blockIdx.x >> 2, qr = blockIdx.x & 3;
    int b = bk >> 3, k = bk & 7;
    int t = threadIdx.x;
    float gts = derived[(size_t)bk*8 + 6];
    __shared__ u64 part[2][NB];
    if (gts >= 0.5f){
        int bu = t & 255, sg = t >> 8;
        u32 np = 0, nn = 0;
        const u32* base = hs + (size_t)b*NSL_H*(KK*NB) + k*NB + bu;
        for (int s = qr*(NSL_H/4) + sg; s < (qr+1)*(NSL_H/4); s += 2){
            u32 h = base[(size_t)s*(KK*NB)];
            np += h >> 16; nn += h & 0xFFFFu;
        }
        part[sg][bu] = ((u64)np << 32) | nn;
        __syncthreads();
        if (t < NB){
            u64 v = part[0][t] + part[1][t];
            if (v) atomicAdd(&ph[(size_t)bk*NB + t], v);   /* ph indexed by bucket (ascending) */
        }
        __threadfence();
    }
    __syncthreads();              /* ALL waves' ph atomics issued before ticket */
    __shared__ u32 lastf;
    if (t == 0){
        u32 tk = __hip_atomic_fetch_add(&tkb[bk], 1u, __ATOMIC_ACQ_REL, __HIP_MEMORY_SCOPE_AGENT);
        lastf = (tk == 3u) ? 1u : 0u;
    }
    __syncthreads();
    if (!lastf) return;
    float lv = 0.f;
    __shared__ u64 wsum[4];
    __shared__ float racc[NB];
    if (gts >= 0.5f){
        __threadfence();
        u64 pack = 0ull, inc = 0ull;
        if (t < NB){
            /* scan position t = descending error order -> bucket (NB-1)-t */
            pack = __hip_atomic_load(&ph[(size_t)bk*NB + (NB-1) - t],
                                     __ATOMIC_ACQUIRE, __HIP_MEMORY_SCOPE_AGENT);
            int lane = t & 63;
            inc = pack;
            #pragma unroll
            for (int off = 1; off < 64; off <<= 1){
                u64 n = __shfl_up(inc, off);
                if (lane >= off) inc += n;
            }
            if (lane == 63) wsum[t >> 6] = inc;
        }
        __syncthreads();
        if (t < 4){
            u64 x = wsum[t];
            #pragma unroll
            for (int off = 1; off < 4; off <<= 1){
                u64 n = __shfl_up(x, off);
                if (t >= off) x += n;
            }
            wsum[t] = x;
        }
        __syncthreads();
        float acc = 0.f;
        if (t < NB){
            int wid = t >> 6;
            u64 excl = inc - pack + (wid ? wsum[wid - 1] : 0ull);
            u32 np2 = (u32)(pack >> 32), nn2 = (u32)pack;
            if (np2 | nn2){
                int bu2 = (NB - 1) - t;     /* actual bucket for this scan position */
                float Pe = (float)(u32)(excl >> 32), Qe = (float)(u32)excl;
                float Pi = Pe + (float)np2, Qi = Qe + (float)nn2;
                float je = 1.f - (gts - Pe)/(gts + Qe);
                float ji = 1.f - (gts - Pi)/(gts + Qi);
                u32 bits = ((u32)(bu2 + BOFF) << 19) | (1u << 18);
                if (bits > 0x40000000u) bits = 0x40000000u;
                acc = __uint_as_float(bits) * (ji - je);
            }
            racc[t] = acc;
        }
        __syncthreads();
        for (int off = 128; off > 0; off >>= 1){
            if (t < off) racc[t] += racc[t + off];
            __syncthreads();
        }
        lv = derived[(size_t)bk*8 + 7] * racc[0];
    }
    if (t == 0){
        __hip_atomic_store(&lov[bk], lv, __ATOMIC_RELEASE, __HIP_MEMORY_SCOPE_AGENT);
        u32 ticket = __hip_atomic_fetch_add(counter, 1u, __ATOMIC_ACQ_REL, __HIP_MEMORY_SCOPE_AGENT);
        if (ticket == 15u){
            float tot = 0.f;
            for (int i = 0; i < 16; i++)
                tot += __hip_atomic_load(&lov[i], __ATOMIC_ACQUIRE, __HIP_MEMORY_SCOPE_AGENT);
            for (int b2 = 0; b2 < BN; b2++){
                float bg = 0.f, fg = 0.f;
                for (int sh = 0; sh < 8; sh++){
                    bg += unfx(bgsh[(size_t)b2*8 + sh]);
                    fg += unfx(bgsh[(size_t)(2+b2)*8 + sh]);
                }
                tot += 10.f*var_part[b2] + (bg + fg)*(1.f/(float)NV);
            }
            out[0] = tot * 0.5f;
        }
    }
}

extern "C" void kernel_launch(void* const* d_in, const int* in_sizes, int n_in,
                              void* d_out, int out_size, void* d_ws, size_t ws_size,
                              hipStream_t stream){
    const float* pred = (const float*)d_in[0];
    const int*   inst = (const int*)d_in[2];
    const int*   lab  = (const int*)d_in[3];
    const void*  cim  = d_in[4];

    char* ws = (char*)d_ws;
    size_t off = 0;
    u32* hs = (u32*)(ws + off);        off += (size_t)BN*NSL_H*KK*NB*4;  /* 4.72 MB */
    size_t small0 = off;
    u64* ssh = (u64*)(ws + off);       off += (size_t)4*BN*KK*12*8;      /* stat shards */
    u64* bgsh = (u64*)(ws + off);      off += (size_t)4*8*8;             /* bg/fg shards */
    u64* ph = (u64*)(ws + off);        off += (size_t)16*NB*8;           /* lovasz partials 32 KB */
    float* derived = (float*)(ws + off); off += (size_t)BN*KK*8*4;
    float* lov = (float*)(ws + off);   off += 16*4;
    float* var_part = (float*)(ws + off); off += 2*4;
    u32* flags = (u32*)(ws + off);     off += 4*4;
    u32* counter = (u32*)(ws + off);   off += 4;
    u32* stk = (u32*)(ws + off);       off += 4;
    u32* tkb = (u32*)(ws + off);       off += 16*4;

    (void)hipMemsetAsync(ws + small0, 0, off - small0, stream);
    k_detect<<<dim3(256), dim3(256), 0, stream>>>((const u32*)cim, BN*NV/4, flags);
    k_stats<<<dim3(NSL_S, BN), dim3(512), 0, stream>>>(pred, inst, lab, cim, flags, ssh, bgsh,
                                                        derived, var_part, stk);
    k_hist<<<dim3(NSL_H, BN), dim3(512), 0, stream>>>(pred, inst, derived, hs, bgsh);
    k_lovasz<<<64, 512, 0, stream>>>(hs, derived, ph, tkb, lov, var_part, bgsh, counter, (float*)d_out);
}

// Round 10
// 76.456 us; speedup vs baseline: 3.7716x; 3.7716x over previous
//
#include <hip/hip_runtime.h>
#include <stdint.h>

typedef unsigned long long u64;
typedef unsigned int u32;

#define BN 2
#define DD 32
#define HH 192
#define WW 192
#define NV (DD*HH*WW)   /* 1179648 */
#define KK 8
#define NSL_S 576       /* k_stats blocks per batch (2048 vox each) */
#define VPB_S 2048
#define NSL_H 288       /* k_hist blocks per batch (4096 vox each) */
#define VPB_H 4096
#define NB 256          /* buckets in window */
#define BOFF 1808       /* 0x38800000>>19 : window floor e = 2^-14 */
#define SCALE 4294967296.0f
#define L2E 1.44269504f

__device__ __forceinline__ u64 fx(float v){ return (u64)(long long)llrintf(v*SCALE); }
__device__ __forceinline__ float unfx(u64 v){ return (float)((double)(long long)v*(1.0/4294967296.0)); }
__device__ __forceinline__ float rcp_f(float x){ return __builtin_amdgcn_rcpf(x); }
__device__ __forceinline__ float exp2_f(float x){ return __builtin_amdgcn_exp2f(x); }
__device__ __forceinline__ float tanh_f(float x){ return 1.f - 2.f*rcp_f(1.f + exp2_f(x*(2.f*L2E))); }
__device__ __forceinline__ float sigm_f(float x){ return rcp_f(1.f + exp2_f(-x*L2E)); }
__device__ __forceinline__ float rfl(float x){ return __uint_as_float(__builtin_amdgcn_readfirstlane((int)__float_as_uint(x))); }

// ---------------- detection of center_images storage layout ----------------
__global__ void k_detect(const u32* __restrict__ w, int nwords, u32* flags){
    u32 fF=0,fB=0,fO=0,f1=0;
    for (int i = blockIdx.x*blockDim.x + threadIdx.x; i < nwords; i += gridDim.x*blockDim.x){
        u32 x = w[i];
        if (x == 0x3F800000u) fF = 1;
        else if (x > 1u) fB = 1;
        else if (x == 1u){ f1 = 1; if (i & 1) fO = 1; }
    }
    if (fF) atomicOr(&flags[0], 1u);
    if (fB) atomicOr(&flags[1], 1u);
    if (fO) atomicOr(&flags[2], 1u);
    if (f1) atomicOr(&flags[3], 1u);
}

// ---------------- per-instance statistics (no tail; kernel boundary = fence) ----------------
// ssh[shard(4)][b][k][12]: 0 cnt<<32|cm_cnt, 1..3 sum_xyz, 4..6 m_sig, 7 m_sig2, 8..10 cm_xyz
__global__ __launch_bounds__(512, 8) void k_stats(
        const float* __restrict__ pred,
        const int* __restrict__ inst, const int* __restrict__ lab,
        const void* __restrict__ cim, const u32* __restrict__ flags,
        u64* __restrict__ ssh, u64* __restrict__ bgsh){
    int sx = blockIdx.x, b = blockIdx.y;
    __shared__ u64 bins[8][4][KK][9];   /* 32 replicas, odd inner stride: 18 KB */
    __shared__ u64 cmb[8][KK][4];        /* rare cm sums, per-wave: 2 KB */
    __shared__ u64 bgsum;
    for (int i = threadIdx.x; i < 8*4*KK*9; i += 512) ((u64*)bins)[i] = 0ull;
    for (int i = threadIdx.x; i < 8*KK*4; i += 512) ((u64*)cmb)[i] = 0ull;
    if (threadIdx.x == 0) bgsum = 0ull;
    __syncthreads();
    int mode = flags[0] ? 2 : (flags[1] ? 1 : (flags[2] ? 0 : (flags[3] ? 3 : 0)));
    const float* pb = pred + (size_t)b*7*NV;
    const int* ib = inst + (size_t)b*NV;
    const int* lb = lab + (size_t)b*NV;
    int wv = threadIdx.x >> 6, lp = threadIdx.x & 3;
    int g = sx*VPB_S + threadIdx.x*4;

    float4 s0v = *(const float4*)&pb[3*(size_t)NV + g];
    float4 s1v = *(const float4*)&pb[4*(size_t)NV + g];
    float4 s2v = *(const float4*)&pb[5*(size_t)NV + g];
    float4 s6v = *(const float4*)&pb[6*(size_t)NV + g];
    int4 iv4 = *(const int4*)&ib[g];
    int4 lb4 = *(const int4*)&lb[g];
    int iy = g / WW;
    int ix = g - iy*WW;
    int iz = iy / HH; iy -= iz*HH;
    u64 fdx = fx(1.f/(WW-1));
    u64 fxm = fx(ix*(1.f/(WW-1)));
    u64 fym = fx(iy*(1.f/(HH-1)));
    u64 fzm = fx(iz*(1.f/(DD-1)));
    u32 cv4 = 0;
    size_t gi = (size_t)b*NV + g;
    if (mode == 0){
        int4 c = *(const int4*)&((const int*)cim)[gi];
        cv4 = (c.x?1u:0u)|(c.y?2u:0u)|(c.z?4u:0u)|(c.w?8u:0u);
    } else if (mode == 1){
        u32 c = *(const u32*)&((const unsigned char*)cim)[gi];
        cv4 = ((c&0xFFu)?1u:0u)|((c&0xFF00u)?2u:0u)|((c&0xFF0000u)?4u:0u)|((c&0xFF000000u)?8u:0u);
    } else if (mode == 2){
        float4 c = *(const float4*)&((const float*)cim)[gi];
        cv4 = (c.x!=0.f?1u:0u)|(c.y!=0.f?2u:0u)|(c.z!=0.f?4u:0u)|(c.w!=0.f?8u:0u);
    } else {
        int4 c0 = *(const int4*)&((const int*)cim)[2*gi];
        int4 c1 = *(const int4*)&((const int*)cim)[2*gi + 4];
        cv4 = (c0.x?1u:0u)|(c0.z?2u:0u)|(c1.x?4u:0u)|(c1.z?8u:0u);
    }
    float s0a[4] = {s0v.x,s0v.y,s0v.z,s0v.w};
    float s1a[4] = {s1v.x,s1v.y,s1v.z,s1v.w};
    float s2a[4] = {s2v.x,s2v.y,s2v.z,s2v.w};
    float s6a[4] = {s6v.x,s6v.y,s6v.z,s6v.w};
    int iva[4] = {iv4.x,iv4.y,iv4.z,iv4.w};
    int lba[4] = {lb4.x,lb4.y,lb4.z,lb4.w};
    float bgacc = 0.f;
    #pragma unroll
    for (int j = 0; j < 4; j++){
        float seed = sigm_f(s6a[j]);
        if (lba[j] == 0) bgacc += seed*seed;
        int iv = iva[j];
        if (iv >= 1 && iv <= KK){
            u64* bn = &bins[wv][lp][iv-1][0];
            u32 cv = (cv4 >> j) & 1u;
            atomicAdd(&bn[0], (1ull << 32) | (u64)cv);
            atomicAdd(&bn[1], fxm + (u64)j*fdx);
            atomicAdd(&bn[2], fym);
            atomicAdd(&bn[3], fzm);
            atomicAdd(&bn[4], fx(s0a[j]));
            atomicAdd(&bn[5], fx(s1a[j]));
            atomicAdd(&bn[6], fx(s2a[j]));
            atomicAdd(&bn[7], fx(s0a[j]*s0a[j] + s1a[j]*s1a[j] + s2a[j]*s2a[j]));
            if (cv){
                u64* cb = &cmb[wv][iv-1][0];
                atomicAdd(&cb[0], fxm + (u64)j*fdx);
                atomicAdd(&cb[1], fym);
                atomicAdd(&cb[2], fzm);
            }
        }
    }
    #pragma unroll
    for (int off = 32; off > 0; off >>= 1) bgacc += __shfl_down(bgacc, off);
    if ((threadIdx.x & 63) == 0 && bgacc != 0.f) atomicAdd(&bgsum, fx(bgacc));
    __syncthreads();
    if (threadIdx.x == 0 && bgsum) atomicAdd(&bgsh[(size_t)b*8 + (sx&7)], bgsum);
    for (int i = threadIdx.x; i < KK*8; i += 512){
        int k = i >> 3, s = i & 7;
        u64 acc = 0ull;
        #pragma unroll
        for (int r = 0; r < 32; r++) acc += bins[r>>2][r&3][k][s];
        if (acc) atomicAdd(&ssh[((size_t)((sx&3)*BN + b)*KK + k)*12 + s], acc);
    }
    for (int i = threadIdx.x; i < KK*3; i += 512){
        int k = i / 3, s = i - k*3;
        u64 acc = 0ull;
        #pragma unroll
        for (int w = 0; w < 8; w++) acc += cmb[w][k][s];
        if (acc) atomicAdd(&ssh[((size_t)((sx&3)*BN + b)*KK + k)*12 + 8 + s], acc);
    }
}

// ---------------- derive per-instance constants (separate tiny kernel) ----------------
// derived[(b*KK+k)*8]: 0..2 s_exp, 3..5 center, 6 gts(count), 7 coef(valid/obj)
__global__ void k_derive(const u64* __restrict__ ssh, float* __restrict__ derived,
                         float* __restrict__ var_part){
    int t = threadIdx.x;
    __shared__ float s_val[16], s_vrk[16], s_obj[2];
    if (t < 16){
        int bb = t >> 3, kq = t & 7;
        u64 st[12];
        #pragma unroll
        for (int s = 0; s < 12; s++){
            u64 a = 0ull;
            #pragma unroll
            for (int sh = 0; sh < 4; sh++)
                a += ssh[((size_t)(sh*BN + bb)*KK + kq)*12 + s];
            st[s] = a;
        }
        float cnt = (float)(long long)(st[0] >> 32);
        float cmc = (float)(u32)(st[0] & 0xFFFFFFFFull);
        float sxs = unfx(st[1]), sys = unfx(st[2]), szs = unfx(st[3]);
        float g0 = unfx(st[4]), g1 = unfx(st[5]), g2 = unfx(st[6]);
        float h = unfx(st[7]);
        float cmx = unfx(st[8]), cmy = unfx(st[9]), cmz = unfx(st[10]);
        float valid = cnt > 0.f ? 1.f : 0.f;
        float safe = fmaxf(cnt, 1.f);
        float c0 = (cmc == 1.f) ? cmx : sxs/safe;
        float c1 = (cmc == 1.f) ? cmy : sys/safe;
        float c2 = (cmc == 1.f) ? cmz : szs/safe;
        float sm0 = g0/safe, sm1 = g1/safe, sm2 = g2/safe;
        float vs = h - 2.f*(sm0*g0 + sm1*g1 + sm2*g2)
                 + (sm0*sm0 + sm1*sm1 + sm2*sm2)*cnt;
        s_vrk[t] = vs / (3.f*safe);
        s_val[t] = valid;
        float* dd = &derived[(size_t)t*8];
        dd[0] = expf(10.f*sm0); dd[1] = expf(10.f*sm1); dd[2] = expf(10.f*sm2);
        dd[3] = c0; dd[4] = c1; dd[5] = c2; dd[6] = cnt;
    }
    __syncthreads();
    if (t < 2){
        float obj = 0.f, vp = 0.f;
        #pragma unroll
        for (int kq = 0; kq < 8; kq++){
            obj += s_val[t*8 + kq];
            vp += s_val[t*8 + kq]*s_vrk[t*8 + kq];
        }
        obj = fmaxf(obj, 1.f);
        var_part[t] = vp / obj;
        s_obj[t] = obj;
    }
    __syncthreads();
    if (t < 16) derived[(size_t)t*8 + 7] = s_val[t]/s_obj[t >> 3];
}

// ---------------- single-pass all-k windowed histogram, 8 vox/thread ----------------
__global__ __launch_bounds__(512, 4) void k_hist(
        const float* __restrict__ pred,
        const int* __restrict__ inst, const float* __restrict__ derived,
        u32* __restrict__ hs, u64* __restrict__ bgsh){
    __shared__ u32 lh[KK*2*NB];   /* 16 KB */
    __shared__ u64 fgfx;
    int sx = blockIdx.x, b = blockIdx.y;
    if (threadIdx.x == 0) fgfx = 0ull;
    for (int i = threadIdx.x; i < KK*2*NB; i += 512) lh[i] = 0u;
    float ax[KK], ay[KK], az[KK], cx[KK], cy[KK], cz[KK];
    const float* db = derived + (size_t)b*KK*8;
    #pragma unroll
    for (int k = 0; k < KK; k++){
        ax[k]=rfl(db[k*8+0])*L2E; ay[k]=rfl(db[k*8+1])*L2E; az[k]=rfl(db[k*8+2])*L2E;
        cx[k]=rfl(db[k*8+3]); cy[k]=rfl(db[k*8+4]); cz[k]=rfl(db[k*8+5]);
    }
    __syncthreads();
    const float* pb = pred + (size_t)b*7*NV;
    const int* ib = inst + (size_t)b*NV;
    int g = sx*VPB_H + threadIdx.x*8;
    const float4* q0 = (const float4*)&pb[g];
    const float4* q1 = (const float4*)&pb[(size_t)NV + g];
    const float4* q2 = (const float4*)&pb[2*(size_t)NV + g];
    const float4* q6 = (const float4*)&pb[6*(size_t)NV + g];
    float4 a0 = q0[0], b0 = q0[1];
    float4 a1 = q1[0], b1 = q1[1];
    float4 a2 = q2[0], b2 = q2[1];
    float4 a6 = q6[0], b6 = q6[1];
    const int4* qi = (const int4*)&ib[g];
    int4 i0 = qi[0], i1 = qi[1];
    int iy = g / WW;
    int ix = g - iy*WW;
    int iz = iy / HH; iy -= iz*HH;
    float xm = ix*(1.f/(WW-1)), ym = iy*(1.f/(HH-1)), zm = iz*(1.f/(DD-1));
    float p0a[8] = {a0.x,a0.y,a0.z,a0.w,b0.x,b0.y,b0.z,b0.w};
    float p1a[8] = {a1.x,a1.y,a1.z,a1.w,b1.x,b1.y,b1.z,b1.w};
    float p2a[8] = {a2.x,a2.y,a2.z,a2.w,b2.x,b2.y,b2.z,b2.w};
    float p6a[8] = {a6.x,a6.y,a6.z,a6.w,b6.x,b6.y,b6.z,b6.w};
    int iva[8] = {i0.x,i0.y,i0.z,i0.w,i1.x,i1.y,i1.z,i1.w};
    float e0[8], e1[8], e2[8], sd[8];
    #pragma unroll
    for (int j = 0; j < 8; j++){
        e0[j] = tanh_f(p0a[j]) + xm + j*(1.f/(WW-1));
        e1[j] = tanh_f(p1a[j]) + ym;
        e2[j] = tanh_f(p2a[j]) + zm;
        sd[j] = sigm_f(p6a[j]);
    }
    float fgacc = 0.f;
    #pragma unroll
    for (int k = 0; k < KK; k++){
        #pragma unroll
        for (int j = 0; j < 8; j++){
            float d0 = e0[j] - cx[k], d1 = e1[j] - cy[k], dz = e2[j] - cz[k];
            float d2 = ax[k]*d0*d0;
            d2 = fmaf(ay[k]*d1, d1, d2);
            d2 = fmaf(az[k]*dz, dz, d2);
            float dist = exp2_f(-d2);               /* L2E folded into a's */
            if (iva[j] == k + 1){
                float e = fmaf(-2.f, dist, 2.f);
                int bu = (int)(__float_as_uint(e) >> 19) - BOFF;
                bu = bu < 0 ? 0 : (bu > NB-1 ? NB-1 : bu);
                atomicAdd(&lh[k*512 + bu], 1u);
                fgacc += (sd[j] - dist)*(sd[j] - dist);
            } else {
                /* e = 2*dist: bits(2x)>>19 == (bits(x)>>19)+16 for normals */
                int bu = (int)(__float_as_uint(dist) >> 19) - (BOFF - 16);
                bu = bu < 0 ? 0 : (bu > NB-1 ? NB-1 : bu);
                atomicAdd(&lh[k*512 + NB + bu], 1u);
            }
        }
    }
    #pragma unroll
    for (int off = 32; off > 0; off >>= 1) fgacc += __shfl_down(fgacc, off);
    if ((threadIdx.x & 63) == 0 && fgacc != 0.f) atomicAdd(&fgfx, fx(fgacc));
    __syncthreads();
    if (threadIdx.x == 0 && fgfx) atomicAdd(&bgsh[(size_t)(2+b)*8 + (sx&7)], fgfx);
    u32* out = hs + ((size_t)b*NSL_H + sx)*(KK*NB);
    for (int i = threadIdx.x; i < KK*NB; i += 512){
        int k = i >> 8, bu = i & 255;
        out[i] = (lh[k*512 + bu] << 16) | lh[k*512 + NB + bu];
    }
}

// ---------------- Lovasz scan over summed hists + fused final (16 blocks) ----------------
__global__ __launch_bounds__(1024) void k_lovasz(
        const u32* __restrict__ hs, const float* __restrict__ derived,
        float* __restrict__ lov, const float* __restrict__ var_part,
        const u64* __restrict__ bgsh, u32* __restrict__ counter,
        float* __restrict__ out){
    int bk = blockIdx.x, b = bk >> 3, k = bk & 7;
    int t = threadIdx.x;
    float gts = derived[(size_t)bk*8 + 6];
    float lv = 0.f;
    __shared__ u64 part[4][NB];
    __shared__ u64 wsum[4];
    __shared__ float racc[NB];
    if (gts >= 0.5f){
        int bu = (NB - 1) - (t & 255);    /* descending error order */
        int sg = t >> 8;
        u32 np = 0, nn = 0;
        const u32* base = hs + (size_t)b*NSL_H*(KK*NB) + k*NB + bu;
        for (int s = sg; s < NSL_H; s += 4){
            u32 h = base[(size_t)s*(KK*NB)];
            np += h >> 16; nn += h & 0xFFFFu;
        }
        part[sg][t & 255] = ((u64)np << 32) | nn;
        __syncthreads();
        u64 pack = 0ull, inc = 0ull;
        if (t < NB){
            pack = part[0][t] + part[1][t] + part[2][t] + part[3][t];
            int lane = t & 63;
            inc = pack;
            #pragma unroll
            for (int off = 1; off < 64; off <<= 1){
                u64 n = __shfl_up(inc, off);
                if (lane >= off) inc += n;
            }
            if (lane == 63) wsum[t >> 6] = inc;
        }
        __syncthreads();
        if (t < 4){
            u64 x = wsum[t];
            #pragma unroll
            for (int off = 1; off < 4; off <<= 1){
                u64 n = __shfl_up(x, off);
                if (t >= off) x += n;
            }
            wsum[t] = x;
        }
        __syncthreads();
        float acc = 0.f;
        if (t < NB){
            int wid = t >> 6;
            u64 excl = inc - pack + (wid ? wsum[wid - 1] : 0ull);
            u32 np2 = (u32)(pack >> 32), nn2 = (u32)pack;
            if (np2 | nn2){
                int bu2 = (NB - 1) - t;
                float Pe = (float)(u32)(excl >> 32), Qe = (float)(u32)excl;
                float Pi = Pe + (float)np2, Qi = Qe + (float)nn2;
                float je = 1.f - (gts - Pe)/(gts + Qe);
                float ji = 1.f - (gts - Pi)/(gts + Qi);
                u32 bits = ((u32)(bu2 + BOFF) << 19) | (1u << 18);
                if (bits > 0x40000000u) bits = 0x40000000u;
                acc = __uint_as_float(bits) * (ji - je);
            }
            racc[t] = acc;
        }
        __syncthreads();
        for (int off = 128; off > 0; off >>= 1){
            if (t < off) racc[t] += racc[t + off];
            __syncthreads();
        }
        lv = derived[(size_t)bk*8 + 7] * racc[0];
    }
    if (t == 0){
        __hip_atomic_store(&lov[bk], lv, __ATOMIC_RELEASE, __HIP_MEMORY_SCOPE_AGENT);
        u32 ticket = __hip_atomic_fetch_add(counter, 1u, __ATOMIC_ACQ_REL, __HIP_MEMORY_SCOPE_AGENT);
        if (ticket == 15u){
            float tot = 0.f;
            for (int i = 0; i < 16; i++)
                tot += __hip_atomic_load(&lov[i], __ATOMIC_ACQUIRE, __HIP_MEMORY_SCOPE_AGENT);
            for (int b2 = 0; b2 < BN; b2++){
                float bg = 0.f, fg = 0.f;
                for (int sh = 0; sh < 8; sh++){
                    bg += unfx(bgsh[(size_t)b2*8 + sh]);
                    fg += unfx(bgsh[(size_t)(2+b2)*8 + sh]);
                }
                tot += 10.f*var_part[b2] + (bg + fg)*(1.f/(float)NV);
            }
            out[0] = tot * 0.5f;
        }
    }
}

extern "C" void kernel_launch(void* const* d_in, const int* in_sizes, int n_in,
                              void* d_out, int out_size, void* d_ws, size_t ws_size,
                              hipStream_t stream){
    const float* pred = (const float*)d_in[0];
    const int*   inst = (const int*)d_in[2];
    const int*   lab  = (const int*)d_in[3];
    const void*  cim  = d_in[4];

    char* ws = (char*)d_ws;
    size_t off = 0;
    u32* hs = (u32*)(ws + off);        off += (size_t)BN*NSL_H*KK*NB*4;  /* 4.72 MB */
    size_t small0 = off;
    u64* ssh = (u64*)(ws + off);       off += (size_t)4*BN*KK*12*8;      /* stat shards */
    u64* bgsh = (u64*)(ws + off);      off += (size_t)4*8*8;             /* bg/fg shards */
    float* derived = (float*)(ws + off); off += (size_t)BN*KK*8*4;
    float* lov = (float*)(ws + off);   off += 16*4;
    float* var_part = (float*)(ws + off); off += 2*4;
    u32* flags = (u32*)(ws + off);     off += 4*4;
    u32* counter = (u32*)(ws + off);   off += 4;

    (void)hipMemsetAsync(ws + small0, 0, off - small0, stream);
    k_detect<<<dim3(256), dim3(256), 0, stream>>>((const u32*)cim, BN*NV/4, flags);
    k_stats<<<dim3(NSL_S, BN), dim3(512), 0, stream>>>(pred, inst, lab, cim, flags, ssh, bgsh);
    k_derive<<<1, 64, 0, stream>>>(ssh, derived, var_part);
    k_hist<<<dim3(NSL_H, BN), dim3(512), 0, stream>>>(pred, inst, derived, hs, bgsh);
    k_lovasz<<<16, 1024, 0, stream>>>(hs, derived, lov, var_part, bgsh, counter, (float*)d_out);
}